// Round 3
// baseline (894.569 us; speedup 1.0000x reference)
//
#include <hip/hip_runtime.h>

// ShapeletEncoder: B=256, T=8192, C=32, CELLS=512, L=16
// per unit (b,s,c): minmax-mid normalize 16 samples, dense 16->32->32->16->10, softmax
//
// Design (round-2 resubmit; rounds 0-2 all failed on GPU acquisition, no data yet):
//  - wave-uniform channel => weights via scalar loads (s_load), shared by 64 lanes
//  - x staged through LDS (transpose from c-fastest to unit-on-lane reads)
//  - tile = 64 units x 16 channels (half of C) per block; 2 blocks/CU overlap
//  - LDS pad: addr = u*273 + l*17 + c  (273 mod 32 = 17, odd -> conflict-free reads)

#define N_UNITS   131072   // B*CELLS = 256*512
#define OUT_PER_U 320      // C*classes = 32*10

__global__ __launch_bounds__(512, 4)
void shapelet_kernel(const float* __restrict__ x,
                     const float* __restrict__ W0, const float* __restrict__ b0,
                     const float* __restrict__ W1, const float* __restrict__ b1,
                     const float* __restrict__ W2, const float* __restrict__ b2,
                     const float* __restrict__ Wf, const float* __restrict__ bf,
                     float* __restrict__ out)
{
    __shared__ float lx[64 * 273];   // 69.9 KB

    const int bid   = blockIdx.x;
    const int tile  = bid >> 1;      // 64-unit tile index
    const int chalf = bid & 1;       // which 16-channel half
    const int unit0 = tile * 64;
    const int tid   = threadIdx.x;

    // ---- stage: 64 units x 16 l x 16 c = 16384 floats (4096 float4)
    {
        const float4* xg = reinterpret_cast<const float4*>(x);
        #pragma unroll
        for (int it = 0; it < 8; ++it) {
            int j  = it * 512 + tid;        // 0..4095
            int c4 = j & 3;                 // float4 within the 16-channel half
            int l  = (j >> 2) & 15;
            int u  = j >> 6;
            float4 v = xg[(size_t)(unit0 + u) * 128 + l * 8 + chalf * 4 + c4];
            int base = u * 273 + l * 17 + c4 * 4;
            lx[base + 0] = v.x;
            lx[base + 1] = v.y;
            lx[base + 2] = v.z;
            lx[base + 3] = v.w;
        }
    }
    __syncthreads();

    const int lane = tid & 63;
    const int wv   = tid >> 6;       // 0..7
    const int u    = lane;           // unit within tile
    const int unit = unit0 + u;

    #pragma unroll 1
    for (int ci = 0; ci < 2; ++ci) {
        const int clocal = wv * 2 + ci;            // 0..15 (uniform per wave)
        const int c      = chalf * 16 + clocal;    // global channel
        const int cu     = __builtin_amdgcn_readfirstlane(c);  // force SGPR -> s_load weights

        const float* w0  = W0 + cu * (16 * 32);
        const float* bb0 = b0 + cu * 32;
        const float* w1  = W1 + cu * (32 * 32);
        const float* bb1 = b1 + cu * 32;
        const float* w2  = W2 + cu * (32 * 16);
        const float* bb2 = b2 + cu * 16;
        const float* wf  = Wf + cu * (16 * 10);
        const float* bbf = bf + cu * 10;

        // load this (unit, channel)'s 16 samples from LDS
        float xx[16];
        #pragma unroll
        for (int l = 0; l < 16; ++l)
            xx[l] = lx[u * 273 + l * 17 + clocal];

        // min-max midpoint normalize
        float mn = xx[0], mx = xx[0];
        #pragma unroll
        for (int l = 1; l < 16; ++l) {
            mn = fminf(mn, xx[l]);
            mx = fmaxf(mx, xx[l]);
        }
        const float mid = 0.5f * (mn + mx);
        #pragma unroll
        for (int l = 0; l < 16; ++l) xx[l] -= mid;

        // layer 0: 16 -> 32
        float h0[32];
        #pragma unroll
        for (int k = 0; k < 32; ++k) h0[k] = bb0[k];
        #pragma unroll
        for (int l = 0; l < 16; ++l) {
            const float xv = xx[l];
            #pragma unroll
            for (int k = 0; k < 32; ++k)
                h0[k] = __builtin_fmaf(xv, w0[l * 32 + k], h0[k]);
        }
        #pragma unroll
        for (int k = 0; k < 32; ++k) h0[k] = fmaxf(h0[k], 0.0f);

        // layer 1: 32 -> 32
        float h1[32];
        #pragma unroll
        for (int m = 0; m < 32; ++m) h1[m] = bb1[m];
        #pragma unroll
        for (int k = 0; k < 32; ++k) {
            const float hv = h0[k];
            #pragma unroll
            for (int m = 0; m < 32; ++m)
                h1[m] = __builtin_fmaf(hv, w1[k * 32 + m], h1[m]);
        }
        #pragma unroll
        for (int m = 0; m < 32; ++m) h1[m] = fmaxf(h1[m], 0.0f);

        // layer 2: 32 -> 16
        float h2[16];
        #pragma unroll
        for (int j = 0; j < 16; ++j) h2[j] = bb2[j];
        #pragma unroll
        for (int k = 0; k < 32; ++k) {
            const float hv = h1[k];
            #pragma unroll
            for (int j = 0; j < 16; ++j)
                h2[j] = __builtin_fmaf(hv, w2[k * 16 + j], h2[j]);
        }
        #pragma unroll
        for (int j = 0; j < 16; ++j) h2[j] = fmaxf(h2[j], 0.0f);

        // final: 16 -> 10
        float lg[10];
        #pragma unroll
        for (int o = 0; o < 10; ++o) lg[o] = bbf[o];
        #pragma unroll
        for (int k = 0; k < 16; ++k) {
            const float hv = h2[k];
            #pragma unroll
            for (int o = 0; o < 10; ++o)
                lg[o] = __builtin_fmaf(hv, wf[k * 10 + o], lg[o]);
        }

        // softmax over 10 classes
        float m = lg[0];
        #pragma unroll
        for (int o = 1; o < 10; ++o) m = fmaxf(m, lg[o]);
        float s = 0.0f;
        #pragma unroll
        for (int o = 0; o < 10; ++o) {
            lg[o] = __expf(lg[o] - m);
            s += lg[o];
        }
        const float r = 1.0f / s;

        // store 10 probs: out[unit*320 + c*10 + o], 8B-aligned -> 5x float2
        float2* op = reinterpret_cast<float2*>(out + (size_t)unit * OUT_PER_U + c * 10);
        #pragma unroll
        for (int o = 0; o < 5; ++o)
            op[o] = make_float2(lg[2 * o] * r, lg[2 * o + 1] * r);
    }
}

extern "C" void kernel_launch(void* const* d_in, const int* in_sizes, int n_in,
                              void* d_out, int out_size, void* d_ws, size_t ws_size,
                              hipStream_t stream) {
    const float* x  = (const float*)d_in[0];
    const float* W0 = (const float*)d_in[1];
    const float* b0 = (const float*)d_in[2];
    const float* W1 = (const float*)d_in[3];
    const float* b1 = (const float*)d_in[4];
    const float* W2 = (const float*)d_in[5];
    const float* b2 = (const float*)d_in[6];
    const float* Wf = (const float*)d_in[7];
    const float* bf = (const float*)d_in[8];
    float* out = (float*)d_out;

    // 131072 units / 64 per tile * 2 channel-halves = 4096 blocks
    shapelet_kernel<<<dim3(4096), dim3(512), 0, stream>>>(
        x, W0, b0, W1, b1, W2, b2, Wf, bf, out);
}

// Round 4
// 731.179 us; speedup vs baseline: 1.2235x; 1.2235x over previous
//
#include <hip/hip_runtime.h>

// ShapeletEncoder: B=256, T=8192, C=32, CELLS=512, L=16
// per unit (b,s,c): minmax-mid normalize 16 samples, dense 16->32->32->16->10, softmax
//
// Round 4 redesign (post-mortem of 640us/VALUBusy43%/VGPR56 baseline):
//  - Root cause: per-channel weights (~9.2KB) via s_load => SGPR file maxed (112),
//    compiler demoted weights to VGPRs and strangled accumulators (VGPR=56 < 64
//    needed for h0+h1) => scratch spills (WRITE +97MB) + lgkmcnt stalls.
//  - Fix: weights live in LDS, read via wave-uniform ds_read_b128 (broadcast,
//    conflict-free). No SGPR pressure, accumulators stay in VGPRs.
//  - Persistent blocks: 256 blocks (1/CU), 512 thr = 8 waves = 8 channels of one
//    channel-group. Weights staged to LDS once per block; 32 unit-tiles of 64
//    units looped with register-prefetched x staging (issue loads before compute,
//    ds_write after next barrier => HBM latency hidden under ~8.8Kcyc compute).
//  - LDS: 8ch x 2304 floats weights (73.7KB) + 64u x 145 floats x-tile (37.1KB)
//    = 110.8KB dynamic. x-tile stride 145 (odd) => <=2-way bank conflicts (free).

#define THREADS 512
#define CPG     8          // channels per group
#define TILE_U  64
#define TPB     32         // tiles per block (64 tstreams * 32 = 2048 tiles)
#define WSTRIDE 2304       // floats per channel in weight LDS
#define XSTRIDE 145        // floats per unit in x LDS (16l * 9 + 1 pad)
#define LDS_FLOATS (CPG * WSTRIDE + TILE_U * XSTRIDE)   // 27712 -> 110848 B

__global__ __launch_bounds__(THREADS, 2)
void shapelet_kernel(const float* __restrict__ x,
                     const float* __restrict__ W0, const float* __restrict__ b0,
                     const float* __restrict__ W1, const float* __restrict__ b1,
                     const float* __restrict__ W2, const float* __restrict__ b2,
                     const float* __restrict__ Wf, const float* __restrict__ bf,
                     float* __restrict__ out)
{
    extern __shared__ float lds[];
    float* wlds = lds;                    // CPG * WSTRIDE
    float* lx   = lds + CPG * WSTRIDE;    // TILE_U * XSTRIDE

    const int tid     = threadIdx.x;
    const int lane    = tid & 63;
    const int wv      = tid >> 6;         // 0..7
    const int g       = blockIdx.x & 3;   // channel group (channels g*8..g*8+7)
    const int tstream = blockIdx.x >> 2;  // 0..63

    // ---- stage weights once per block: wave wv stages channel cw = wv
    {
        const int c = g * CPG + wv;
        float* wd = wlds + wv * WSTRIDE;
        // layout (floats): w0@0[512], b0@512[32], w1@544[1024], b1@1568[32],
        //                  w2@1600[512], b2@2112[16], wfT@2128[160], bf@2288[10]
        const float* s0 = W0 + c * 512;
        for (int i = lane; i < 512; i += 64) wd[i] = s0[i];
        if (lane < 32) wd[512 + lane] = b0[c * 32 + lane];
        const float* s1 = W1 + c * 1024;
        for (int i = lane; i < 1024; i += 64) wd[544 + i] = s1[i];
        if (lane < 32) wd[1568 + lane] = b1[c * 32 + lane];
        const float* s2 = W2 + c * 512;
        for (int i = lane; i < 512; i += 64) wd[1600 + i] = s2[i];
        if (lane < 16) wd[2112 + lane] = b2[c * 16 + lane];
        // Wf stored TRANSPOSED: wfT[o*16 + k] = Wf[c*160 + k*10 + o]
        const float* sf = Wf + c * 160;
        for (int i = lane; i < 160; i += 64) {
            int k = i / 10, o = i - k * 10;
            wd[2128 + o * 16 + k] = sf[i];
        }
        if (lane < 10) wd[2288 + lane] = bf[c * 10 + lane];
    }

    // ---- prefetch x-tile 0 into registers (4 float4/thread)
    const float4* xg = reinterpret_cast<const float4*>(x);
    float4 pre[4];
    {
        size_t unit0 = (size_t)(tstream * TPB) * TILE_U;
        #pragma unroll
        for (int it = 0; it < 4; ++it) {
            int m = it * THREADS + tid;         // 0..2047
            int uu = m >> 5, l = (m >> 1) & 15, q = m & 1;
            pre[it] = xg[(unit0 + uu) * 128 + l * 8 + g * 2 + q];
        }
    }

    const int cw = wv;                           // wave-uniform channel slot
    const float* wb = wlds + cw * WSTRIDE;
    const int u = lane;

    for (int j = 0; j < TPB; ++j) {
        const int tile  = tstream * TPB + j;
        const int unit0 = tile * TILE_U;

        __syncthreads();   // previous tile's lx reads complete
        // ---- ds_write prefetched x (implicit vmcnt wait via reg dep)
        #pragma unroll
        for (int it = 0; it < 4; ++it) {
            int m = it * THREADS + tid;
            int uu = m >> 5, l = (m >> 1) & 15, q = m & 1;
            float* d = lx + uu * XSTRIDE + l * 9 + q * 4;
            d[0] = pre[it].x; d[1] = pre[it].y; d[2] = pre[it].z; d[3] = pre[it].w;
        }
        __syncthreads();

        // ---- issue next tile's global loads NOW (hide HBM under compute, T14)
        if (j + 1 < TPB) {
            size_t unit0n = (size_t)(unit0 + TILE_U);
            #pragma unroll
            for (int it = 0; it < 4; ++it) {
                int m = it * THREADS + tid;
                int uu = m >> 5, l = (m >> 1) & 15, q = m & 1;
                pre[it] = xg[(unit0n + uu) * 128 + l * 8 + g * 2 + q];
            }
        }

        // ---- per-(unit,channel) MLP; weights via wave-uniform LDS broadcast
        float xx[16];
        #pragma unroll
        for (int l = 0; l < 16; ++l)
            xx[l] = lx[u * XSTRIDE + l * 9 + cw];

        float mn = xx[0], mx = xx[0];
        #pragma unroll
        for (int l = 1; l < 16; ++l) {
            mn = fminf(mn, xx[l]);
            mx = fmaxf(mx, xx[l]);
        }
        const float mid = 0.5f * (mn + mx);
        #pragma unroll
        for (int l = 0; l < 16; ++l) xx[l] -= mid;

        // layer 0: 16 -> 32
        float h0[32];
        #pragma unroll
        for (int k4 = 0; k4 < 8; ++k4) {
            float4 bb = *reinterpret_cast<const float4*>(wb + 512 + k4 * 4);
            h0[k4*4+0] = bb.x; h0[k4*4+1] = bb.y; h0[k4*4+2] = bb.z; h0[k4*4+3] = bb.w;
        }
        #pragma unroll
        for (int l = 0; l < 16; ++l) {
            const float xv = xx[l];
            #pragma unroll
            for (int k4 = 0; k4 < 8; ++k4) {
                float4 w = *reinterpret_cast<const float4*>(wb + l * 32 + k4 * 4);
                h0[k4*4+0] = fmaf(xv, w.x, h0[k4*4+0]);
                h0[k4*4+1] = fmaf(xv, w.y, h0[k4*4+1]);
                h0[k4*4+2] = fmaf(xv, w.z, h0[k4*4+2]);
                h0[k4*4+3] = fmaf(xv, w.w, h0[k4*4+3]);
            }
        }
        #pragma unroll
        for (int k = 0; k < 32; ++k) h0[k] = fmaxf(h0[k], 0.0f);

        // layer 1: 32 -> 32
        float h1[32];
        #pragma unroll
        for (int m4 = 0; m4 < 8; ++m4) {
            float4 bb = *reinterpret_cast<const float4*>(wb + 1568 + m4 * 4);
            h1[m4*4+0] = bb.x; h1[m4*4+1] = bb.y; h1[m4*4+2] = bb.z; h1[m4*4+3] = bb.w;
        }
        #pragma unroll
        for (int k = 0; k < 32; ++k) {
            const float hv = h0[k];
            #pragma unroll
            for (int m4 = 0; m4 < 8; ++m4) {
                float4 w = *reinterpret_cast<const float4*>(wb + 544 + k * 32 + m4 * 4);
                h1[m4*4+0] = fmaf(hv, w.x, h1[m4*4+0]);
                h1[m4*4+1] = fmaf(hv, w.y, h1[m4*4+1]);
                h1[m4*4+2] = fmaf(hv, w.z, h1[m4*4+2]);
                h1[m4*4+3] = fmaf(hv, w.w, h1[m4*4+3]);
            }
        }
        #pragma unroll
        for (int k = 0; k < 32; ++k) h1[k] = fmaxf(h1[k], 0.0f);

        // layer 2: 32 -> 16
        float h2[16];
        #pragma unroll
        for (int j4 = 0; j4 < 4; ++j4) {
            float4 bb = *reinterpret_cast<const float4*>(wb + 2112 + j4 * 4);
            h2[j4*4+0] = bb.x; h2[j4*4+1] = bb.y; h2[j4*4+2] = bb.z; h2[j4*4+3] = bb.w;
        }
        #pragma unroll
        for (int k = 0; k < 32; ++k) {
            const float hv = h1[k];
            #pragma unroll
            for (int j4 = 0; j4 < 4; ++j4) {
                float4 w = *reinterpret_cast<const float4*>(wb + 1600 + k * 16 + j4 * 4);
                h2[j4*4+0] = fmaf(hv, w.x, h2[j4*4+0]);
                h2[j4*4+1] = fmaf(hv, w.y, h2[j4*4+1]);
                h2[j4*4+2] = fmaf(hv, w.z, h2[j4*4+2]);
                h2[j4*4+3] = fmaf(hv, w.w, h2[j4*4+3]);
            }
        }
        #pragma unroll
        for (int k = 0; k < 16; ++k) h2[k] = fmaxf(h2[k], 0.0f);

        // final: 16 -> 10 (transposed wf => dot per output)
        float lg[10];
        #pragma unroll
        for (int o = 0; o < 10; ++o) {
            float acc = wb[2288 + o];
            #pragma unroll
            for (int k4 = 0; k4 < 4; ++k4) {
                float4 w = *reinterpret_cast<const float4*>(wb + 2128 + o * 16 + k4 * 4);
                acc = fmaf(h2[k4*4+0], w.x, acc);
                acc = fmaf(h2[k4*4+1], w.y, acc);
                acc = fmaf(h2[k4*4+2], w.z, acc);
                acc = fmaf(h2[k4*4+3], w.w, acc);
            }
            lg[o] = acc;
        }

        // softmax over 10 classes
        float mxl = lg[0];
        #pragma unroll
        for (int o = 1; o < 10; ++o) mxl = fmaxf(mxl, lg[o]);
        float s = 0.0f;
        #pragma unroll
        for (int o = 0; o < 10; ++o) {
            lg[o] = __expf(lg[o] - mxl);
            s += lg[o];
        }
        const float r = 1.0f / s;

        float2* op = reinterpret_cast<float2*>(
            out + (size_t)(unit0 + u) * 320 + (g * CPG + cw) * 10);
        #pragma unroll
        for (int o = 0; o < 5; ++o)
            op[o] = make_float2(lg[2*o] * r, lg[2*o+1] * r);
    }
}

extern "C" void kernel_launch(void* const* d_in, const int* in_sizes, int n_in,
                              void* d_out, int out_size, void* d_ws, size_t ws_size,
                              hipStream_t stream) {
    const float* x  = (const float*)d_in[0];
    const float* W0 = (const float*)d_in[1];
    const float* b0 = (const float*)d_in[2];
    const float* W1 = (const float*)d_in[3];
    const float* b1 = (const float*)d_in[4];
    const float* W2 = (const float*)d_in[5];
    const float* b2 = (const float*)d_in[6];
    const float* Wf = (const float*)d_in[7];
    const float* bf = (const float*)d_in[8];
    float* out = (float*)d_out;

    const size_t shmem = LDS_FLOATS * sizeof(float);   // 110848 B
    // idempotent, not a stream op — safe under graph capture (runs eagerly)
    hipFuncSetAttribute((const void*)shapelet_kernel,
                        hipFuncAttributeMaxDynamicSharedMemorySize, (int)shmem);

    // 64 tile-streams * 4 channel-groups = 256 blocks (1 per CU, persistent)
    shapelet_kernel<<<dim3(256), dim3(THREADS), shmem, stream>>>(
        x, W0, b0, W1, b1, W2, b2, Wf, bf, out);
}

// Round 6
// 636.411 us; speedup vs baseline: 1.4056x; 1.1489x over previous
//
#include <hip/hip_runtime.h>

// ShapeletEncoder: B=256, T=8192, C=32, CELLS=512, L=16
// per unit (b,s,c): minmax-mid normalize 16 samples, dense 16->32->32->16->10, softmax
//
// Round 6 = round-5 resubmit (GPU acquisition timeout, no data).
// Round 5 design (post-mortem of 491us / VGPR=56 / real-VALUBusy~29% / FETCH 2x):
//  - r4 was LATENCY-bound: dynamic LDS (110KB) caps at 2 waves/SIMD, and the
//    compiler pressure-squeezed to 56 VGPRs (targeting an occupancy LDS forbids),
//    killing ds_read lookahead. VALU issue itself was already near the 128us floor.
//  - Fix A: 1024-thread blocks (16 waves = 4 waves/SIMD): waves (cw,uh) = channel
//    cw (0..7), unit-half uh. 128 units/tile staged. LDS 73.7K wt + 74.2K x = 148K.
//  - Fix B: amdgpu_waves_per_eu(4,4): compiler budget = 128 VGPR/wave, stop
//    squeezing, keep weight ds_read_b128 results in flight.
//  - Fix C: sibling channel-group blocks (g=0..3, same units) share XCD:
//    hw XCD = dispatch_index % 8, so decode xcd=bid&7 => all 4 siblings same L2;
//    each uses 32B/128B of every x line => line fetched once per XCD now.

#define THREADS 1024
#define CPG     8          // channels per group
#define TILE_U  128        // units per tile (2 waves per channel)
#define TPB     16         // tiles per block: 64 ustreams * 16 * 128 = 131072 units
#define WSTRIDE 2304       // floats per channel in weight LDS
#define XSTRIDE 145        // floats per unit in x LDS (16l * 9 + 1 pad)
#define LDS_FLOATS (CPG * WSTRIDE + TILE_U * XSTRIDE)   // 36992 -> 147968 B

__global__ __attribute__((amdgpu_waves_per_eu(4, 4)))
void shapelet_kernel(const float* __restrict__ x,
                     const float* __restrict__ W0, const float* __restrict__ b0,
                     const float* __restrict__ W1, const float* __restrict__ b1,
                     const float* __restrict__ W2, const float* __restrict__ b2,
                     const float* __restrict__ Wf, const float* __restrict__ bf,
                     float* __restrict__ out)
{
    extern __shared__ float lds[];
    float* wlds = lds;                    // CPG * WSTRIDE
    float* lx   = lds + CPG * WSTRIDE;    // TILE_U * XSTRIDE

    const int tid  = threadIdx.x;
    const int lane = tid & 63;
    const int wv   = tid >> 6;            // 0..15
    const int cw   = wv & 7;              // channel slot (wave-uniform)
    const int uh   = wv >> 3;             // unit half (0/1)

    // ---- block decode: siblings (same units, different channel-group) on same XCD
    const int bid     = blockIdx.x;
    const int xcd     = bid & 7;
    const int r       = bid >> 3;         // 0..31
    const int g       = r & 3;            // channel group (channels g*8..g*8+7)
    const int q       = r >> 2;           // 0..7
    const int ustream = xcd * 8 + q;      // 0..63

    // ---- stage weights once per block: wave-pair (cw, uh) stages channel cw
    {
        const int c = g * CPG + cw;
        float* wd = wlds + cw * WSTRIDE;
        const int i0 = lane + uh * 64;    // stride-128 split across the pair
        // layout (floats): w0@0[512], b0@512[32], w1@544[1024], b1@1568[32],
        //                  w2@1600[512], b2@2112[16], wfT@2128[160], bf@2288[10]
        const float* s0 = W0 + c * 512;
        for (int i = i0; i < 512; i += 128) wd[i] = s0[i];
        const float* s1 = W1 + c * 1024;
        for (int i = i0; i < 1024; i += 128) wd[544 + i] = s1[i];
        const float* s2 = W2 + c * 512;
        for (int i = i0; i < 512; i += 128) wd[1600 + i] = s2[i];
        // Wf stored TRANSPOSED: wfT[o*16 + k] = Wf[c*160 + k*10 + o]
        const float* sf = Wf + c * 160;
        for (int i = i0; i < 160; i += 128) {
            int k = i / 10, o = i - k * 10;
            wd[2128 + o * 16 + k] = sf[i];
        }
        if (uh == 0) {
            if (lane < 32) wd[512  + lane] = b0[c * 32 + lane];
            if (lane < 32) wd[1568 + lane] = b1[c * 32 + lane];
        } else {
            if (lane < 16) wd[2112 + lane] = b2[c * 16 + lane];
            if (lane < 10) wd[2288 + lane] = bf[c * 10 + lane];
        }
    }

    // ---- prefetch x-tile 0 into registers (4 float4/thread = 4096 float4/tile)
    const float4* xg = reinterpret_cast<const float4*>(x);
    float4 pre[4];
    {
        size_t unit0 = (size_t)(ustream * TPB) * TILE_U;
        #pragma unroll
        for (int it = 0; it < 4; ++it) {
            int m = it * THREADS + tid;          // 0..4095
            int uu = m >> 5, l = (m >> 1) & 15, qq = m & 1;
            pre[it] = xg[(unit0 + uu) * 128 + l * 8 + g * 2 + qq];
        }
    }

    const float* wb = wlds + cw * WSTRIDE;   // wave-uniform weight base
    const int u = lane + uh * 64;            // unit within tile (0..127)

    #pragma unroll 1
    for (int j = 0; j < TPB; ++j) {
        const int unit0 = (ustream * TPB + j) * TILE_U;

        __syncthreads();   // previous tile's lx reads complete
        // ---- ds_write prefetched x
        #pragma unroll
        for (int it = 0; it < 4; ++it) {
            int m = it * THREADS + tid;
            int uu = m >> 5, l = (m >> 1) & 15, qq = m & 1;
            float* d = lx + uu * XSTRIDE + l * 9 + qq * 4;
            d[0] = pre[it].x; d[1] = pre[it].y; d[2] = pre[it].z; d[3] = pre[it].w;
        }
        __syncthreads();

        // ---- issue next tile's global loads NOW (hide HBM under compute)
        if (j + 1 < TPB) {
            size_t unit0n = (size_t)(unit0 + TILE_U);
            #pragma unroll
            for (int it = 0; it < 4; ++it) {
                int m = it * THREADS + tid;
                int uu = m >> 5, l = (m >> 1) & 15, qq = m & 1;
                pre[it] = xg[(unit0n + uu) * 128 + l * 8 + g * 2 + qq];
            }
        }

        // ---- per-(unit,channel) MLP; weights via wave-uniform LDS broadcast
        float xx[16];
        #pragma unroll
        for (int l = 0; l < 16; ++l)
            xx[l] = lx[u * XSTRIDE + l * 9 + cw];

        float mn = xx[0], mx = xx[0];
        #pragma unroll
        for (int l = 1; l < 16; ++l) {
            mn = fminf(mn, xx[l]);
            mx = fmaxf(mx, xx[l]);
        }
        const float mid = 0.5f * (mn + mx);
        #pragma unroll
        for (int l = 0; l < 16; ++l) xx[l] -= mid;

        // layer 0: 16 -> 32
        float h0[32];
        #pragma unroll
        for (int k4 = 0; k4 < 8; ++k4) {
            float4 bb = *reinterpret_cast<const float4*>(wb + 512 + k4 * 4);
            h0[k4*4+0] = bb.x; h0[k4*4+1] = bb.y; h0[k4*4+2] = bb.z; h0[k4*4+3] = bb.w;
        }
        #pragma unroll
        for (int l = 0; l < 16; ++l) {
            const float xv = xx[l];
            #pragma unroll
            for (int k4 = 0; k4 < 8; ++k4) {
                float4 w = *reinterpret_cast<const float4*>(wb + l * 32 + k4 * 4);
                h0[k4*4+0] = fmaf(xv, w.x, h0[k4*4+0]);
                h0[k4*4+1] = fmaf(xv, w.y, h0[k4*4+1]);
                h0[k4*4+2] = fmaf(xv, w.z, h0[k4*4+2]);
                h0[k4*4+3] = fmaf(xv, w.w, h0[k4*4+3]);
            }
        }
        #pragma unroll
        for (int k = 0; k < 32; ++k) h0[k] = fmaxf(h0[k], 0.0f);

        // layer 1: 32 -> 32
        float h1[32];
        #pragma unroll
        for (int m4 = 0; m4 < 8; ++m4) {
            float4 bb = *reinterpret_cast<const float4*>(wb + 1568 + m4 * 4);
            h1[m4*4+0] = bb.x; h1[m4*4+1] = bb.y; h1[m4*4+2] = bb.z; h1[m4*4+3] = bb.w;
        }
        #pragma unroll
        for (int k = 0; k < 32; ++k) {
            const float hv = h0[k];
            #pragma unroll
            for (int m4 = 0; m4 < 8; ++m4) {
                float4 w = *reinterpret_cast<const float4*>(wb + 544 + k * 32 + m4 * 4);
                h1[m4*4+0] = fmaf(hv, w.x, h1[m4*4+0]);
                h1[m4*4+1] = fmaf(hv, w.y, h1[m4*4+1]);
                h1[m4*4+2] = fmaf(hv, w.z, h1[m4*4+2]);
                h1[m4*4+3] = fmaf(hv, w.w, h1[m4*4+3]);
            }
        }
        #pragma unroll
        for (int k = 0; k < 32; ++k) h1[k] = fmaxf(h1[k], 0.0f);

        // layer 2: 32 -> 16
        float h2[16];
        #pragma unroll
        for (int j4 = 0; j4 < 4; ++j4) {
            float4 bb = *reinterpret_cast<const float4*>(wb + 2112 + j4 * 4);
            h2[j4*4+0] = bb.x; h2[j4*4+1] = bb.y; h2[j4*4+2] = bb.z; h2[j4*4+3] = bb.w;
        }
        #pragma unroll
        for (int k = 0; k < 32; ++k) {
            const float hv = h1[k];
            #pragma unroll
            for (int j4 = 0; j4 < 4; ++j4) {
                float4 w = *reinterpret_cast<const float4*>(wb + 1600 + k * 16 + j4 * 4);
                h2[j4*4+0] = fmaf(hv, w.x, h2[j4*4+0]);
                h2[j4*4+1] = fmaf(hv, w.y, h2[j4*4+1]);
                h2[j4*4+2] = fmaf(hv, w.z, h2[j4*4+2]);
                h2[j4*4+3] = fmaf(hv, w.w, h2[j4*4+3]);
            }
        }
        #pragma unroll
        for (int k = 0; k < 16; ++k) h2[k] = fmaxf(h2[k], 0.0f);

        // final: 16 -> 10 (transposed wf => dot per output)
        float lg[10];
        #pragma unroll
        for (int o = 0; o < 10; ++o) {
            float acc = wb[2288 + o];
            #pragma unroll
            for (int k4 = 0; k4 < 4; ++k4) {
                float4 w = *reinterpret_cast<const float4*>(wb + 2128 + o * 16 + k4 * 4);
                acc = fmaf(h2[k4*4+0], w.x, acc);
                acc = fmaf(h2[k4*4+1], w.y, acc);
                acc = fmaf(h2[k4*4+2], w.z, acc);
                acc = fmaf(h2[k4*4+3], w.w, acc);
            }
            lg[o] = acc;
        }

        // softmax over 10 classes
        float mxl = lg[0];
        #pragma unroll
        for (int o = 1; o < 10; ++o) mxl = fmaxf(mxl, lg[o]);
        float s = 0.0f;
        #pragma unroll
        for (int o = 0; o < 10; ++o) {
            lg[o] = __expf(lg[o] - mxl);
            s += lg[o];
        }
        const float rr = 1.0f / s;

        float2* op = reinterpret_cast<float2*>(
            out + (size_t)(unit0 + u) * 320 + (g * CPG + cw) * 10);
        #pragma unroll
        for (int o = 0; o < 5; ++o)
            op[o] = make_float2(lg[2*o] * rr, lg[2*o+1] * rr);
    }
}

extern "C" void kernel_launch(void* const* d_in, const int* in_sizes, int n_in,
                              void* d_out, int out_size, void* d_ws, size_t ws_size,
                              hipStream_t stream) {
    const float* x  = (const float*)d_in[0];
    const float* W0 = (const float*)d_in[1];
    const float* b0 = (const float*)d_in[2];
    const float* W1 = (const float*)d_in[3];
    const float* b1 = (const float*)d_in[4];
    const float* W2 = (const float*)d_in[5];
    const float* b2 = (const float*)d_in[6];
    const float* Wf = (const float*)d_in[7];
    const float* bf = (const float*)d_in[8];
    float* out = (float*)d_out;

    const size_t shmem = LDS_FLOATS * sizeof(float);   // 147968 B
    hipFuncSetAttribute((const void*)shapelet_kernel,
                        hipFuncAttributeMaxDynamicSharedMemorySize, (int)shmem);

    // 256 blocks (1/CU), 1024 threads: 64 unit-streams x 4 channel-groups
    shapelet_kernel<<<dim3(256), dim3(THREADS), shmem, stream>>>(
        x, W0, b0, W1, b1, W2, b2, Wf, bf, out);
}